// Round 6
// baseline (670.557 us; speedup 1.0000x reference)
//
#include <hip/hip_runtime.h>
#include <hip/hip_bf16.h>

// ---------------- problem constants ----------------
#define NPTS 131072
#define PER  2738            // 37*37*2
#define NBKT 5476
#define NCHUNK 2048          // NPTS/64

typedef short v8s __attribute__((ext_vector_type(8)));
typedef float v4f __attribute__((ext_vector_type(4)));
#define MFMA16(a,b,c) __builtin_amdgcn_mfma_f32_16x16x32_bf16(a,b,c,0,0,0)

__device__ __forceinline__ unsigned short f2b(float x) {
    unsigned u = __float_as_uint(x);
    unsigned r = (u + 0x7FFFu + ((u >> 16) & 1u)) >> 16;
    return (unsigned short)r;
}
__device__ __forceinline__ unsigned pack2(float a, float b) {
    return (unsigned)f2b(a) | ((unsigned)f2b(b) << 16);
}
__device__ __forceinline__ float b2f(unsigned short s) {
    return __uint_as_float((unsigned)s << 16);
}

// k-dim redistribution across kg groups (replaces LDS round-trip).
// dest (l15,kg), frag covering k = 32*ks + kg*8 + [0,8): first int2 from lane
// l15+16*((2kg)&3), second from l15+16*((2kg+1)&3); value pp[2ks] for kg<2 else pp[2ks+1].
__device__ __forceinline__ v8s redist(int2 a, int2 b, int lane) {
    int l15 = lane & 15, kg = lane >> 4;
    int m0 = l15 + 16 * ((2 * kg) & 3);
    int m1 = l15 + 16 * ((2 * kg + 1) & 3);
    int ax0 = __shfl(a.x, m0, 64), ay0 = __shfl(a.y, m0, 64);
    int ax1 = __shfl(a.x, m1, 64), ay1 = __shfl(a.y, m1, 64);
    int bx0 = __shfl(b.x, m0, 64), by0 = __shfl(b.y, m0, 64);
    int bx1 = __shfl(b.x, m1, 64), by1 = __shfl(b.y, m1, 64);
    bool hi = kg >= 2;
    union { int i[4]; v8s v; } u;
    u.i[0] = hi ? bx0 : ax0;
    u.i[1] = hi ? by0 : ay0;
    u.i[2] = hi ? bx1 : ax1;
    u.i[3] = hi ? by1 : ay1;
    return u.v;
}

// ---------------- sort kernels (verified) ----------------
__global__ void k_zero(int* a, int* b, int* c, int* d) {
    int t = blockIdx.x * 256 + threadIdx.x;
    if (t < 8192) { a[t] = 0; b[t] = 0; c[t] = 0; d[t] = 0; }
}

__global__ void k_keys(const int* __restrict__ coords, int* cntx, int* cnty) {
    int j = blockIdx.x * 256 + threadIdx.x;
    if (j >= NPTS) return;
    int b = coords[4*j], z = coords[4*j+1], y = coords[4*j+2], x = coords[4*j+3];
    int wcx = x / 13, wcy = y / 13, wcz = z / 32;
    atomicAdd(&cntx[b * PER + wcx * 74 + wcy * 2 + wcz], 1);
    atomicAdd(&cnty[b * PER + wcy * 74 + wcx * 2 + wcz], 1);
}

__global__ __launch_bounds__(256) void k_bscan(const int* __restrict__ cntx, int* offx,
                                               const int* __restrict__ cnty, int* offy) {
    const int* cnt = blockIdx.x ? cnty : cntx;
    int* off = blockIdx.x ? offy : offx;
    __shared__ int part[256];
    int t = threadIdx.x;
    const int CH = (NBKT + 255) / 256;
    int s = 0;
    for (int i = 0; i < CH; i++) { int idx = t * CH + i; if (idx < NBKT) s += cnt[idx]; }
    part[t] = s;
    __syncthreads();
    for (int d = 1; d < 256; d <<= 1) {
        int v = (t >= d) ? part[t - d] : 0;
        __syncthreads();
        part[t] += v;
        __syncthreads();
    }
    int base = (t == 0) ? 0 : part[t - 1];
    for (int i = 0; i < CH; i++) {
        int idx = t * CH + i;
        if (idx < NBKT) { off[idx] = base; base += cnt[idx]; }
    }
}

__global__ void k_scatter(const int* __restrict__ coords,
                          const int* __restrict__ offx, int* curx, int* bkx,
                          const int* __restrict__ offy, int* cury, int* bky) {
    int j = blockIdx.x * 256 + threadIdx.x;
    if (j >= NPTS) return;
    int b = coords[4*j], z = coords[4*j+1], y = coords[4*j+2], x = coords[4*j+3];
    int wcx = x / 13, wcy = y / 13, wcz = z / 32;
    int cx = x - wcx * 13, cy = y - wcy * 13, cz = z - wcz * 32;
    int px = offx[b*PER + wcx*74 + wcy*2 + wcz] + atomicAdd(&curx[b*PER + wcx*74 + wcy*2 + wcz], 1);
    bkx[px] = ((cx * 416 + cy * 32 + cz) << 17) | j;
    int py = offy[b*PER + wcy*74 + wcx*2 + wcz] + atomicAdd(&cury[b*PER + wcy*74 + wcx*2 + wcz], 1);
    bky[py] = ((cy * 416 + cx * 32 + cz) << 17) | j;
}

__global__ __launch_bounds__(256) void k_bsort(const int* offx, const int* cntx, const int* bkx, int* ix,
                                               const int* offy, const int* cnty, const int* bky, int* iy) {
    const int* off; const int* cnt; const int* bk; int* oidx;
    if (blockIdx.y == 0) { off = offx; cnt = cntx; bk = bkx; oidx = ix; }
    else                 { off = offy; cnt = cnty; bk = bky; oidx = iy; }
    int b = blockIdx.x;
    int n = cnt[b];
    if (n <= 0) return;
    int base = off[b];
    __shared__ int keys[256];
    int t = threadIdx.x;
    if (t < n) keys[t] = bk[base + t];
    __syncthreads();
    if (t < n) {
        int kv = keys[t];
        int r = 0;
        for (int j = 0; j < n; j++) r += (keys[j] < kv);
        oidx[base + r] = kv & 0x1FFFF;
    }
}

// ---------------- weight convert+transpose: WT[w][d][c] = W[w][c][d] (bf16) ----------------
struct WP { const float* p[10]; };
__global__ void k_cvtw(WP wp, unsigned short* __restrict__ WT) {
    int i = blockIdx.x * 256 + threadIdx.x;   // 10*16384
    int w = i >> 14, r = i & 16383, c = r >> 7, d = r & 127;
    float v = wp.p[w][c * 128 + d];
    if (w == 0 || w == 5) v *= 0.17677669529663687f;   // fold DH^-0.5 into Wq
    WT[(size_t)w * 16384 + d * 128 + c] = f2b(v);
}

// ---------------- k_qkv: Q,K̂,V projections (MFMA), coalesced X staging ----------------
// Q,K̂ swapped-form -> row-major [tok][128]; K pre-decayed by gamma^(63-s).
// V normal-form -> vtb [chunk][h][e][s].
__global__ __launch_bounds__(256) void k_qkv(const float* __restrict__ src,
        const int* __restrict__ idx,
        const unsigned short* __restrict__ WTq, const unsigned short* __restrict__ WTk,
        const unsigned short* __restrict__ WTv,
        unsigned short* __restrict__ qb, unsigned short* __restrict__ kbh,
        unsigned short* __restrict__ vtb) {
    __shared__ unsigned short Xl[64 * 136];   // bf16 X tile, pad 136
    const int chunk = blockIdx.x;
    const int t = threadIdx.x, w = t >> 6, lane = t & 63, l15 = lane & 15, kg = lane >> 4;
    // coalesced gather+convert: each 32-lane group reads one 512B row
#pragma unroll
    for (int i = 0; i < 8; i++) {
        int r = i * 8 + (t >> 5);
        int col = (t & 31) * 4;
        int srow = idx[chunk * 64 + r];
        float4 v = *(const float4*)(src + (size_t)srow * 128 + col);
        uint2 p; p.x = pack2(v.x, v.y); p.y = pack2(v.z, v.w);
        *(uint2*)(Xl + r * 136 + col) = p;
    }
    __syncthreads();
    const int sloc = w * 16 + l15;
    const int rtok = chunk * 64 + sloc;
    v8s xf[4];
#pragma unroll
    for (int ks = 0; ks < 4; ks++)
        xf[ks] = *(const v8s*)(Xl + sloc * 136 + ks * 32 + kg * 8);
    float w63[4];
#pragma unroll
    for (int h = 0; h < 4; h++) {
        float l2g = log2f(1.f - exp2f(-5.f - (float)h));
        w63[h] = exp2f((float)(63 - sloc) * l2g);
    }
    // Q (swapped: D col = token)
#pragma unroll
    for (int dt = 0; dt < 8; dt++) {
        v4f acc = {0.f, 0.f, 0.f, 0.f};
#pragma unroll
        for (int ks = 0; ks < 4; ks++) {
            v8s wf = *(const v8s*)(WTq + (size_t)(dt * 16 + l15) * 128 + ks * 32 + kg * 8);
            acc = MFMA16(wf, xf[ks], acc);
        }
        int2 p; p.x = pack2(acc[0], acc[1]); p.y = pack2(acc[2], acc[3]);
        *(int2*)(qb + (size_t)rtok * 128 + dt * 16 + kg * 4) = p;
    }
    // K̂ (swapped, pre-decayed by gamma^(63-sloc))
#pragma unroll
    for (int dt = 0; dt < 8; dt++) {
        v4f acc = {0.f, 0.f, 0.f, 0.f};
#pragma unroll
        for (int ks = 0; ks < 4; ks++) {
            v8s wf = *(const v8s*)(WTk + (size_t)(dt * 16 + l15) * 128 + ks * 32 + kg * 8);
            acc = MFMA16(wf, xf[ks], acc);
        }
        float dec = w63[dt >> 1];
        int2 p; p.x = pack2(acc[0] * dec, acc[1] * dec); p.y = pack2(acc[2] * dec, acc[3] * dec);
        *(int2*)(kbh + (size_t)rtok * 128 + dt * 16 + kg * 4) = p;
    }
    // V (normal: D row = token) -> transposed store [e][s]
#pragma unroll
    for (int et = 0; et < 8; et++) {
        v4f acc = {0.f, 0.f, 0.f, 0.f};
#pragma unroll
        for (int ks = 0; ks < 4; ks++) {
            v8s wf = *(const v8s*)(WTv + (size_t)(et * 16 + l15) * 128 + ks * 32 + kg * 8);
            acc = MFMA16(xf[ks], wf, acc);
        }
        int e_glob = et * 16 + l15, h = e_glob >> 5, e = e_glob & 31, s0 = w * 16 + kg * 4;
        int2 p; p.x = pack2(acc[0], acc[1]); p.y = pack2(acc[2], acc[3]);
        *(int2*)(vtb + ((size_t)(chunk * 4 + h) * 2048) + e * 64 + s0) = p;
    }
}

// ---------------- k_chA: A[d][e] = sum_s K̂[s,d] V[s,e] per chunk/head ----------------
__global__ __launch_bounds__(256) void k_chA(const unsigned short* __restrict__ kbh,
                                             const unsigned short* __restrict__ vtb,
                                             float* __restrict__ At) {
    __shared__ unsigned short kt[128 * 72];   // K̂^T [d][s]
    const int chunk = blockIdx.x;
    const int t = threadIdx.x, w = t >> 6, lane = t & 63, l15 = lane & 15, kg = lane >> 4;
#pragma unroll
    for (int i = 0; i < 4; i++) {
        int linear = i * 256 + t;             // 0..1023
        int s = linear >> 4, cs = linear & 15;
        v8s kv = *(const v8s*)(kbh + (size_t)(chunk * 64 + s) * 128 + cs * 8);
#pragma unroll
        for (int j = 0; j < 8; j++) kt[(cs * 8 + j) * 72 + s] = (unsigned short)kv[j];
    }
    __syncthreads();
    const int h = w, g = chunk >> 6, c = chunk & 63;
    size_t base = ((size_t)(g * 4 + h) * 64 + c) * 1024;
#pragma unroll
    for (int dt2 = 0; dt2 < 2; dt2++)
#pragma unroll
    for (int et2 = 0; et2 < 2; et2++) {
        v4f acc = {0.f, 0.f, 0.f, 0.f};
#pragma unroll
        for (int ks2 = 0; ks2 < 2; ks2++) {
            v8s af = *(const v8s*)(kt + (h * 32 + dt2 * 16 + l15) * 72 + ks2 * 32 + kg * 8);
            v8s bf = *(const v8s*)(vtb + (size_t)(chunk * 4 + h) * 2048 + (et2 * 16 + l15) * 64 + ks2 * 32 + kg * 8);
            acc = MFMA16(af, bf, acc);
        }
        *(v4f*)(At + base + (et2 * 16 + l15) * 32 + dt2 * 16 + kg * 4) = acc;
    }
}

// ---------------- serial state scan, prefetch-all (exclusive prefix, gamma^64 decay) ----------------
__global__ __launch_bounds__(256) void k_sscan(const float* __restrict__ At,
                                               unsigned short* __restrict__ Sbt) {
    int b = blockIdx.x, gh = b >> 2, q = b & 3, h = gh & 3;
    int p = q * 256 + threadIdx.x;
    float gT = exp2f(64.f * log2f(1.f - exp2f(-5.f - (float)h)));
    size_t base = (size_t)gh * 65536 + p;
    float a[64];
#pragma unroll
    for (int c = 0; c < 64; c++) a[c] = At[base + (size_t)c * 1024];
    float s = 0.f;
#pragma unroll
    for (int c = 0; c < 64; c++) {
        Sbt[base + (size_t)c * 1024] = f2b(s);
        s = gT * s + a[c];
    }
}

// ---------------- fused attention + gate + output + residual (ZERO LDS, no barriers) ----------------
__global__ __launch_bounds__(256) void k_attnf(const float* __restrict__ src,
        const int* __restrict__ idx,
        const unsigned short* __restrict__ qb, const unsigned short* __restrict__ kbh,
        const unsigned short* __restrict__ vtb, const unsigned short* __restrict__ Sbt,
        const unsigned short* __restrict__ WTg, const unsigned short* __restrict__ WTo,
        float* __restrict__ outp) {
    const int chunk = blockIdx.x;
    const int t = threadIdx.x, w = t >> 6, lane = t & 63, l15 = lane & 15, kg = lane >> 4;
    const int rl = w * 16 + l15;
    const int rtok = chunk * 64 + rl;
    float l2g[4];
#pragma unroll
    for (int h = 0; h < 4; h++) l2g[h] = log2f(1.f - exp2f(-5.f - (float)h));
    v4f yacc[8];
#pragma unroll
    for (int i = 0; i < 8; i++) yacc[i] = (v4f){0.f, 0.f, 0.f, 0.f};
    const size_t sb = ((size_t)(chunk >> 6) * 256 + (chunk & 63)) * 1024;
#pragma unroll
    for (int h = 0; h < 4; h++) {
        float grow = exp2f((float)(rl - 63) * l2g[h]);   // gamma^(r-63), undoes K̂ decay + applies D
        float gc   = exp2f((float)(rl + 1)  * l2g[h]);   // gamma^(r+1) for cross term
        v8s qf = *(const v8s*)(qb + (size_t)rtok * 128 + h * 32 + kg * 8);
        // QK̂^T swapped: D[s][r], lane col = own token rl
        int2 pp[4];
#pragma unroll
        for (int st = 0; st < 4; st++) {
            v8s kf = *(const v8s*)(kbh + (size_t)(chunk * 64 + st * 16 + l15) * 128 + h * 32 + kg * 8);
            v4f Tf = MFMA16(kf, qf, ((v4f){0.f, 0.f, 0.f, 0.f}));
            int s0 = st * 16 + kg * 4;
            float v0 = (rl >= s0    ) ? Tf[0] * grow : 0.f;
            float v1 = (rl >= s0 + 1) ? Tf[1] * grow : 0.f;
            float v2 = (rl >= s0 + 2) ? Tf[2] * grow : 0.f;
            float v3 = (rl >= s0 + 3) ? Tf[3] * grow : 0.f;
            pp[st].x = pack2(v0, v1); pp[st].y = pack2(v2, v3);
        }
        // P-ext (cross B-frag): gamma^(r+1) * q̂[kg*8..+8] — fully lane-local
        union { int i[4]; v8s v; } pe;
        pe.i[0] = pack2(b2f((unsigned short)qf[0]) * gc, b2f((unsigned short)qf[1]) * gc);
        pe.i[1] = pack2(b2f((unsigned short)qf[2]) * gc, b2f((unsigned short)qf[3]) * gc);
        pe.i[2] = pack2(b2f((unsigned short)qf[4]) * gc, b2f((unsigned short)qf[5]) * gc);
        pe.i[3] = pack2(b2f((unsigned short)qf[6]) * gc, b2f((unsigned short)qf[7]) * gc);
        v8s pf0 = redist(pp[0], pp[1], lane);
        v8s pf1 = redist(pp[2], pp[3], lane);
        // PV + cross: y^T[e][r]
#pragma unroll
        for (int et = 0; et < 2; et++) {
            v4f acc = yacc[h * 2 + et];
            size_t vbase = (size_t)(chunk * 4 + h) * 2048 + (et * 16 + l15) * 64;
            v8s vf0 = *(const v8s*)(vtb + vbase + kg * 8);
            v8s vf1 = *(const v8s*)(vtb + vbase + 32 + kg * 8);
            acc = MFMA16(vf0, pf0, acc);
            acc = MFMA16(vf1, pf1, acc);
            v8s sf = *(const v8s*)(Sbt + sb + (size_t)h * 65536 + (et * 16 + l15) * 32 + kg * 8);
            acc = MFMA16(sf, pe.v, acc);
            yacc[h * 2 + et] = acc;
        }
    }
    // ---- gate: z = y * silu(x@Wg), kept in registers ----
    const int srow = idx[rtok];
    const float* xr = src + (size_t)srow * 128;
    v8s xg[4];
#pragma unroll
    for (int ks = 0; ks < 4; ks++) {
        int c0 = ks * 32 + kg * 8;
        float4 a = *(const float4*)(xr + c0);
        float4 b = *(const float4*)(xr + c0 + 4);
        union { int i[4]; v8s v; } u;
        u.i[0] = pack2(a.x, a.y); u.i[1] = pack2(a.z, a.w);
        u.i[2] = pack2(b.x, b.y); u.i[3] = pack2(b.z, b.w);
        xg[ks] = u.v;
    }
    int2 zp[8];
#pragma unroll
    for (int ct = 0; ct < 8; ct++) {
        v4f g = {0.f, 0.f, 0.f, 0.f};
#pragma unroll
        for (int ks = 0; ks < 4; ks++) {
            v8s wf = *(const v8s*)(WTg + (size_t)(ct * 16 + l15) * 128 + ks * 32 + kg * 8);
            g = MFMA16(wf, xg[ks], g);
        }
        v4f yv = yacc[ct];
        float z0 = yv[0] * (g[0] / (1.f + __expf(-g[0])));
        float z1 = yv[1] * (g[1] / (1.f + __expf(-g[1])));
        float z2 = yv[2] * (g[2] / (1.f + __expf(-g[2])));
        float z3 = yv[3] * (g[3] / (1.f + __expf(-g[3])));
        zp[ct].x = pack2(z0, z1); zp[ct].y = pack2(z2, z3);
    }
    // ---- out: (z@Wo) + residual, scatter ----
    v8s zf[4];
#pragma unroll
    for (int ks = 0; ks < 4; ks++) zf[ks] = redist(zp[2 * ks], zp[2 * ks + 1], lane);
#pragma unroll
    for (int cot = 0; cot < 8; cot++) {
        v4f acc = {0.f, 0.f, 0.f, 0.f};
#pragma unroll
        for (int ks = 0; ks < 4; ks++) {
            v8s wf = *(const v8s*)(WTo + (size_t)(cot * 16 + l15) * 128 + ks * 32 + kg * 8);
            acc = MFMA16(wf, zf[ks], acc);
        }
        int c0 = cot * 16 + kg * 4;
        float4 xres = *(const float4*)(xr + c0);
        float4 o;
        o.x = xres.x + acc[0]; o.y = xres.y + acc[1];
        o.z = xres.z + acc[2]; o.w = xres.w + acc[3];
        *(float4*)(outp + (size_t)srow * 128 + c0) = o;
    }
}

// ---------------- host side ----------------
static void run_pass(const float* src, const int* idx, const unsigned short* WT, int wbase,
                     unsigned short* qb, unsigned short* kbh, unsigned short* vtb,
                     float* At, unsigned short* Sbt, float* out, hipStream_t stream) {
    k_qkv<<<NCHUNK, 256, 0, stream>>>(src, idx, WT + (size_t)(wbase+0)*16384,
                                      WT + (size_t)(wbase+1)*16384, WT + (size_t)(wbase+2)*16384,
                                      qb, kbh, vtb);
    k_chA<<<NCHUNK, 256, 0, stream>>>(kbh, vtb, At);
    k_sscan<<<512, 256, 0, stream>>>(At, Sbt);
    k_attnf<<<NCHUNK, 256, 0, stream>>>(src, idx, qb, kbh, vtb, Sbt,
                                        WT + (size_t)(wbase+3)*16384, WT + (size_t)(wbase+4)*16384, out);
}

extern "C" void kernel_launch(void* const* d_in, const int* in_sizes, int n_in,
                              void* d_out, int out_size, void* d_ws, size_t ws_size,
                              hipStream_t stream) {
    const float* feats  = (const float*)d_in[0];
    const int*   coords = (const int*)d_in[1];
    float* out = (float*)d_out;

    char* wptr = (char*)d_ws;
    unsigned short* qb  = (unsigned short*)wptr; wptr += (size_t)NPTS * 128 * 2;   // 32MB
    unsigned short* kbh = (unsigned short*)wptr; wptr += (size_t)NPTS * 128 * 2;   // 32MB
    unsigned short* vtb = (unsigned short*)wptr; wptr += (size_t)NPTS * 128 * 2;   // 32MB
    float* At           = (float*)wptr;          wptr += (size_t)NCHUNK * 4096 * 4; // 32MB
    unsigned short* Sbt = (unsigned short*)wptr; wptr += (size_t)NCHUNK * 4096 * 2; // 16MB
    unsigned short* WT  = (unsigned short*)wptr; wptr += (size_t)10 * 16384 * 2;    // 320KB
    int* ix   = (int*)wptr; wptr += (size_t)NPTS * 4;
    int* iy   = (int*)wptr; wptr += (size_t)NPTS * 4;
    int* bkx  = (int*)wptr; wptr += (size_t)NPTS * 4;
    int* bky  = (int*)wptr; wptr += (size_t)NPTS * 4;
    int* cntx = (int*)wptr; wptr += 8192 * 4;
    int* cnty = (int*)wptr; wptr += 8192 * 4;
    int* offx = (int*)wptr; wptr += 8192 * 4;
    int* offy = (int*)wptr; wptr += 8192 * 4;
    int* curx = (int*)wptr; wptr += 8192 * 4;
    int* cury = (int*)wptr; wptr += 8192 * 4;

    // weights -> transposed bf16
    WP wp;
    for (int i = 0; i < 10; i++) wp.p[i] = (const float*)d_in[2 + i];
    k_cvtw<<<640, 256, 0, stream>>>(wp, WT);

    // stable argsort of both keys
    k_zero<<<32, 256, 0, stream>>>(cntx, cnty, curx, cury);
    k_keys<<<(NPTS + 255) / 256, 256, 0, stream>>>(coords, cntx, cnty);
    k_bscan<<<2, 256, 0, stream>>>(cntx, offx, cnty, offy);
    k_scatter<<<(NPTS + 255) / 256, 256, 0, stream>>>(coords, offx, curx, bkx, offy, cury, bky);
    k_bsort<<<dim3(NBKT, 2), 256, 0, stream>>>(offx, cntx, bkx, ix, offy, cnty, bky, iy);

    // pass 0 (x-order): feats -> out ; pass 1 (y-order): out -> out
    run_pass(feats, ix, WT, 0, qb, kbh, vtb, At, Sbt, out, stream);
    run_pass(out,   iy, WT, 5, qb, kbh, vtb, At, Sbt, out, stream);
}